// Round 1
// baseline (255.047 us; speedup 1.0000x reference)
//
#include <hip/hip_runtime.h>
#include <hip/hip_bf16.h>

// ---------------------------------------------------------------------------
// LengthRegulator:
//   x   [B, T, C]  float32
//   dur [B, T]     int32 (>=0 after clamp)
//   out [B, T_out, C] where out[b,t,:] = x[b, idx, :],
//     idx = upper_bound(cumsum(dur[b,:]), t) clamped to T-1.
// T_out is recovered from out_size: T_out = out_size / (B*C).
// ---------------------------------------------------------------------------

#define LR_T 512  // tokens per row (fixed by setup_inputs)

// Kernel 1: per-row inclusive cumsum of dur into cum (workspace).
// One block per batch row, LR_T threads, Hillis-Steele scan in LDS.
__global__ void lr_cumsum_kernel(const int* __restrict__ dur,
                                 int* __restrict__ cum, int T) {
    __shared__ int s[LR_T];
    const int b = blockIdx.x;
    const int t = threadIdx.x;
    int v = dur[(size_t)b * T + t];
    v = v > 0 ? v : 0;  // jnp.maximum(dur, 0)
    s[t] = v;
    __syncthreads();
    for (int off = 1; off < LR_T; off <<= 1) {
        int add = (t >= off) ? s[t - off] : 0;
        __syncthreads();
        s[t] += add;
        __syncthreads();
    }
    cum[(size_t)b * T + t] = s[t];
}

// Kernel 2: one block per output frame (b, t). All lanes perform the same
// (wave-uniform) binary search over cum[b,:] (2 KB, L1-resident), then do a
// coalesced float4 row copy: 128 threads x 16 B = 2 KB = one C=512 fp32 row.
__global__ void lr_gather_kernel(const float* __restrict__ x,
                                 const int* __restrict__ cum,
                                 float* __restrict__ out,
                                 int T, int T_out, int C) {
    const int t = blockIdx.x;   // output frame
    const int b = blockIdx.y;   // batch row

    const int* crow = cum + (size_t)b * T;
    // upper_bound: first j with crow[j] > t  (searchsorted side='right')
    int lo = 0, hi = T;
    while (lo < hi) {
        int mid = (lo + hi) >> 1;
        if (crow[mid] > t) hi = mid; else lo = mid + 1;
    }
    int idx = lo < (T - 1) ? lo : (T - 1);  // overflow -> last token

    const float4* __restrict__ src =
        (const float4*)(x + ((size_t)b * T + idx) * C);
    float4* __restrict__ dst =
        (float4*)(out + ((size_t)b * T_out + t) * C);
    dst[threadIdx.x] = src[threadIdx.x];
}

extern "C" void kernel_launch(void* const* d_in, const int* in_sizes, int n_in,
                              void* d_out, int out_size, void* d_ws, size_t ws_size,
                              hipStream_t stream) {
    const float* x   = (const float*)d_in[0];
    const int*   dur = (const int*)d_in[1];
    float*       out = (float*)d_out;

    const int B  = 32;
    const int BT = in_sizes[1];            // B*T
    const int T  = BT / B;                 // 512
    const int C  = in_sizes[0] / BT;       // 512
    const int T_out = out_size / (B * C);  // data-dependent, encoded in out_size

    int* cum = (int*)d_ws;                 // B*T ints = 64 KB scratch

    lr_cumsum_kernel<<<B, T, 0, stream>>>(dur, cum, T);

    dim3 grid(T_out, B);
    lr_gather_kernel<<<grid, C / 4, 0, stream>>>(x, cum, out, T, T_out, C);
}

// Round 2
// 239.222 us; speedup vs baseline: 1.0662x; 1.0662x over previous
//
#include <hip/hip_runtime.h>
#include <hip/hip_bf16.h>

// ---------------------------------------------------------------------------
// LengthRegulator:
//   x   [B, T, C]  float32
//   dur [B, T]     int32
//   out [B, T_out, C] where out[b,t,:] = x[b, idx, :],
//     idx = upper_bound(cumsum(max(dur,0))[b,:], t) clamped to T-1.
// T_out recovered from out_size: T_out = out_size / (B*C).
//
// Two kernels:
//  1) per-row LDS scan + LDS binary search for every output frame
//     -> srcoff[b*T_out + t] = b*T + idx   (flat source-row map, ~B*T_out*4 B)
//  2) pure grid-stride float4 gather-copy driven by srcoff (memory-bound).
// ---------------------------------------------------------------------------

#define LR_T 512  // tokens per row (fixed by setup_inputs)

__global__ void lr_index_kernel(const int* __restrict__ dur,
                                int* __restrict__ srcoff,
                                int T, int T_out) {
    __shared__ int s[LR_T];
    const int b = blockIdx.x;
    const int tid = threadIdx.x;

    int v = dur[(size_t)b * T + tid];
    v = v > 0 ? v : 0;  // jnp.maximum(dur, 0)
    s[tid] = v;
    __syncthreads();
    // Hillis-Steele inclusive scan in LDS.
    for (int off = 1; off < LR_T; off <<= 1) {
        int add = (tid >= off) ? s[tid - off] : 0;
        __syncthreads();
        s[tid] += add;
        __syncthreads();
    }

    // For each output frame t of this row: upper_bound(s, t), clamp, emit
    // the flat source row offset b*T + idx.
    int* rowmap = srcoff + (size_t)b * T_out;
    const int base = b * T;
    for (int t = tid; t < T_out; t += LR_T) {
        int lo = 0, hi = T;
        while (lo < hi) {
            int mid = (lo + hi) >> 1;
            if (s[mid] > t) hi = mid; else lo = mid + 1;
        }
        int idx = lo < (T - 1) ? lo : (T - 1);
        rowmap[t] = base + idx;
    }
}

// Pure coalesced copy: out4[i] = x4[srcoff[i >> c4shift]*c4 + (i & (c4-1))]
__global__ void lr_copy_kernel(const float4* __restrict__ x4,
                               const int* __restrict__ srcoff,
                               float4* __restrict__ out4,
                               long n4, int c4, int c4shift) {
    long i = (long)blockIdx.x * blockDim.x + threadIdx.x;
    const long stride = (long)gridDim.x * blockDim.x;
    const long mask = c4 - 1;
    for (; i < n4; i += stride) {
        const int row = (int)(i >> c4shift);
        const long lane = i & mask;
        out4[i] = x4[(size_t)srcoff[row] * c4 + lane];
    }
}

extern "C" void kernel_launch(void* const* d_in, const int* in_sizes, int n_in,
                              void* d_out, int out_size, void* d_ws, size_t ws_size,
                              hipStream_t stream) {
    const float* x   = (const float*)d_in[0];
    const int*   dur = (const int*)d_in[1];
    float*       out = (float*)d_out;

    const int B  = 32;
    const int BT = in_sizes[1];            // B*T
    const int T  = BT / B;                 // 512
    const int C  = in_sizes[0] / BT;       // 512
    const int T_out = out_size / (B * C);  // data-dependent, encoded in out_size

    int* srcoff = (int*)d_ws;              // B*T_out ints

    lr_index_kernel<<<B, LR_T, 0, stream>>>(dur, srcoff, T, T_out);

    const long n4 = (long)out_size / 4;    // total float4 elements in out
    const int c4 = C / 4;                  // 128
    int c4shift = 0;
    while ((1 << c4shift) < c4) ++c4shift; // log2(c4) = 7

    int threads = 256;
    long want = (n4 + threads - 1) / threads;
    int blocks = (int)(want < 8192 ? want : 8192);
    lr_copy_kernel<<<blocks, threads, 0, stream>>>(
        (const float4*)x, srcoff, (float4*)out, n4, c4, c4shift);
}